// Round 1
// baseline (82.624 us; speedup 1.0000x reference)
//
#include <hip/hip_runtime.h>

// Problem constants (match reference)
constexpr int B_IMG = 8;
constexpr int A_ANCH = 150000;
constexpr int C_CLS = 10;
constexpr int TPB = 256;
constexpr int APT = 2;   // anchors per thread -> 16B-aligned float4 attribute loads per anchor pair

// ws layout: [B doubles att_sum][B doubles rl_sum][B ints num_pos]
__global__ __launch_bounds__(TPB) void focal_main(
    const float* __restrict__ attr,   // (B, A, C)
    const float* __restrict__ regr,   // (B, A, 4)
    const float* __restrict__ anch,   // (A, 4)
    const float* __restrict__ ann,    // (B, 14)
    double* __restrict__ att_acc,
    double* __restrict__ rl_acc,
    int* __restrict__ np_acc)
{
    const int b = blockIdx.y;
    const int base = (blockIdx.x * TPB + threadIdx.x) * APT;

    // annotation is wave-uniform (b uniform per block) -> scalar-cached loads
    const float* annb = ann + b * 14;
    const float bx0 = annb[0], by0 = annb[1], bx1 = annb[2], by1 = annb[3];
    float lab[C_CLS];
#pragma unroll
    for (int c = 0; c < C_CLS; ++c) lab[c] = annb[4 + c];

    const float gw_raw = bx1 - bx0;
    const float gh_raw = by1 - by0;
    const float area = gw_raw * gh_raw;
    const float gcx = bx0 + 0.5f * gw_raw;
    const float gcy = by0 + 0.5f * gh_raw;
    const float gw = fmaxf(gw_raw, 1.0f);
    const float gh = fmaxf(gh_raw, 1.0f);

    const float TH  = (float)(1.0 / 9.0);
    const float SUB = (float)(0.5 / 9.0);
    const float PHI = (float)(1.0 - 0.0001);  // clip hi

    float att_sum = 0.0f;
    float rl_sum = 0.0f;
    int np = 0;

#pragma unroll
    for (int k = 0; k < APT; ++k) {
        const int a = base + k;
        if (a < A_ANCH) {
            const float4 an = *reinterpret_cast<const float4*>(anch + (size_t)a * 4);
            const float aw = an.z - an.x;
            const float ah = an.w - an.y;
            float iw = fminf(an.z, bx1) - fmaxf(an.x, bx0);
            float ih = fminf(an.w, by1) - fmaxf(an.y, by0);
            iw = fmaxf(iw, 0.0f);
            ih = fmaxf(ih, 0.0f);
            const float inter = iw * ih;
            const float uni = fmaxf(aw * ah + area - inter, 1e-8f);
            const float iou = inter / uni;
            const bool pos = (iou >= 0.5f);
            const bool neg = (iou < 0.4f);

            if (pos || neg) {
                // attribute row: 10 floats; for even a the pair (2 anchors = 20 floats)
                // starts 16B-aligned; let the compiler vectorize these contiguous reads.
                const float* ap = attr + ((size_t)b * A_ANCH + a) * C_CLS;
#pragma unroll
                for (int c = 0; c < C_CLS; ++c) {
                    float p = ap[c];
                    p = fminf(fmaxf(p, 1e-4f), PHI);
                    const float tgt = pos ? lab[c] : 0.0f;
                    float loss;
                    if (tgt == 1.0f) {
                        const float q = 1.0f - p;
                        loss = 0.25f * (q * q) * (-logf(p));
                    } else {
                        loss = 0.75f * (p * p) * (-logf(1.0f - p));
                    }
                    att_sum += loss;
                }
            }
            if (pos) {
                ++np;
                const float acx = an.x + 0.5f * aw;
                const float acy = an.y + 0.5f * ah;
                const float t0 = ((gcx - acx) / aw) / 0.1f;
                const float t1 = ((gcy - acy) / ah) / 0.1f;
                const float t2 = logf(gw / aw) / 0.2f;
                const float t3 = logf(gh / ah) / 0.2f;
                const float4 r = *reinterpret_cast<const float4*>(regr + ((size_t)b * A_ANCH + a) * 4);
                float d;
                d = fabsf(t0 - r.x); rl_sum += (d <= TH) ? 4.5f * d * d : d - SUB;
                d = fabsf(t1 - r.y); rl_sum += (d <= TH) ? 4.5f * d * d : d - SUB;
                d = fabsf(t2 - r.z); rl_sum += (d <= TH) ? 4.5f * d * d : d - SUB;
                d = fabsf(t3 - r.w); rl_sum += (d <= TH) ? 4.5f * d * d : d - SUB;
            }
        }
    }

    // wave (64-lane) reduce
#pragma unroll
    for (int off = 32; off > 0; off >>= 1) {
        att_sum += __shfl_down(att_sum, off);
        rl_sum  += __shfl_down(rl_sum, off);
        np      += __shfl_down(np, off);
    }

    __shared__ float s_att[TPB / 64];
    __shared__ float s_rl[TPB / 64];
    __shared__ int   s_np[TPB / 64];
    const int wave = threadIdx.x >> 6;
    const int lane = threadIdx.x & 63;
    if (lane == 0) { s_att[wave] = att_sum; s_rl[wave] = rl_sum; s_np[wave] = np; }
    __syncthreads();
    if (threadIdx.x == 0) {
        float a0 = 0.0f, r0 = 0.0f;
        int n0 = 0;
#pragma unroll
        for (int w = 0; w < TPB / 64; ++w) { a0 += s_att[w]; r0 += s_rl[w]; n0 += s_np[w]; }
        atomicAdd(&att_acc[b], (double)a0);
        if (r0 != 0.0f) atomicAdd(&rl_acc[b], (double)r0);
        if (n0 != 0)    atomicAdd(&np_acc[b], n0);
    }
}

__global__ void focal_finalize(
    const double* __restrict__ att_acc,
    const double* __restrict__ rl_acc,
    const int* __restrict__ np_acc,
    float* __restrict__ out)
{
    if (threadIdx.x == 0 && blockIdx.x == 0) {
        double am = 0.0, rm = 0.0;
        for (int b = 0; b < B_IMG; ++b) {
            const int np = np_acc[b];
            const double npf = (double)(np > 0 ? np : 1);
            am += att_acc[b] / npf;
            if (np > 0) rm += rl_acc[b] / (npf * 4.0);
        }
        out[0] = (float)(am / (double)B_IMG);
        out[1] = (float)(rm / (double)B_IMG);
    }
}

extern "C" void kernel_launch(void* const* d_in, const int* in_sizes, int n_in,
                              void* d_out, int out_size, void* d_ws, size_t ws_size,
                              hipStream_t stream) {
    const float* attr = (const float*)d_in[0];   // attributes (B,A,C)
    const float* regr = (const float*)d_in[1];   // regressions (B,A,4)
    const float* anch = (const float*)d_in[2];   // anchors (1,A,4)
    const float* ann  = (const float*)d_in[3];   // annotations (B,14)
    float* out = (float*)d_out;

    double* att_acc = (double*)d_ws;
    double* rl_acc  = att_acc + B_IMG;
    int*    np_acc  = (int*)(rl_acc + B_IMG);

    // zero the accumulators every launch (harness does not re-poison between replays)
    hipMemsetAsync(d_ws, 0, 2 * B_IMG * sizeof(double) + B_IMG * sizeof(int), stream);

    dim3 grid((A_ANCH + TPB * APT - 1) / (TPB * APT), B_IMG);
    focal_main<<<grid, TPB, 0, stream>>>(attr, regr, anch, ann, att_acc, rl_acc, np_acc);
    focal_finalize<<<1, 64, 0, stream>>>(att_acc, rl_acc, np_acc, out);
}

// Round 2
// 49.992 us; speedup vs baseline: 1.6527x; 1.6527x over previous
//
#include <hip/hip_runtime.h>

// Problem constants (match reference)
constexpr int B_IMG = 8;
constexpr int A_ANCH = 150000;
constexpr int C_CLS = 10;
constexpr int TPB = 256;
// Each thread owns an EVEN anchor pair: 20 attr floats = 80 contiguous bytes,
// 16B-aligned -> five float4 loads issued upfront (no scalar strided gathers).

// ws layout: [B doubles att_sum][B doubles rl_sum][B ints num_pos]
__global__ __launch_bounds__(TPB) void focal_main(
    const float* __restrict__ attr,   // (B, A, C)
    const float* __restrict__ regr,   // (B, A, 4)
    const float* __restrict__ anch,   // (A, 4)
    const float* __restrict__ ann,    // (B, 14)
    double* __restrict__ att_acc,
    double* __restrict__ rl_acc,
    int* __restrict__ np_acc)
{
    const int b = blockIdx.y;
    const int a0 = (blockIdx.x * TPB + threadIdx.x) * 2;
    const bool valid = (a0 < A_ANCH);   // A even, so a0 valid => a0+1 valid

    // ---- issue ALL global loads for this thread upfront (independent, vectorized) ----
    float4 at4[5];   // 2 anchors x 10 classes
    float4 an4[2];   // 2 anchor boxes
    if (valid) {
        const float4* ap = reinterpret_cast<const float4*>(attr + ((size_t)b * A_ANCH + a0) * C_CLS);
#pragma unroll
        for (int j = 0; j < 5; ++j) at4[j] = ap[j];
        const float4* anp = reinterpret_cast<const float4*>(anch) + a0;
        an4[0] = anp[0];
        an4[1] = anp[1];
    }

    // annotation is wave-uniform -> scalar loads
    const float* annb = ann + b * 14;
    const float bx0 = annb[0], by0 = annb[1], bx1 = annb[2], by1 = annb[3];
    float lab[C_CLS];
#pragma unroll
    for (int c = 0; c < C_CLS; ++c) lab[c] = annb[4 + c];

    const float gw_raw = bx1 - bx0;
    const float gh_raw = by1 - by0;
    const float area = gw_raw * gh_raw;
    const float gcx = bx0 + 0.5f * gw_raw;
    const float gcy = by0 + 0.5f * gh_raw;
    const float gw = fmaxf(gw_raw, 1.0f);
    const float gh = fmaxf(gh_raw, 1.0f);

    const float TH  = (float)(1.0 / 9.0);
    const float SUB = (float)(0.5 / 9.0);
    const float PHI = (float)(1.0 - 0.0001);

    float att_sum = 0.0f;
    float rl_sum = 0.0f;
    int np = 0;

    if (valid) {
        // scatter the vector loads into a statically-indexed register array
        float av[20];
#pragma unroll
        for (int j = 0; j < 5; ++j) {
            av[4 * j + 0] = at4[j].x;
            av[4 * j + 1] = at4[j].y;
            av[4 * j + 2] = at4[j].z;
            av[4 * j + 3] = at4[j].w;
        }

#pragma unroll
        for (int k = 0; k < 2; ++k) {
            const float ax0 = an4[k].x, ay0 = an4[k].y, ax1 = an4[k].z, ay1 = an4[k].w;
            const float aw = ax1 - ax0;
            const float ah = ay1 - ay0;
            float iw = fminf(ax1, bx1) - fmaxf(ax0, bx0);
            float ih = fminf(ay1, by1) - fmaxf(ay0, by0);
            iw = fmaxf(iw, 0.0f);
            ih = fmaxf(ih, 0.0f);
            const float inter = iw * ih;
            const float uni = fmaxf(aw * ah + area - inter, 1e-8f);
            const float iou = inter / uni;
            const bool pos = (iou >= 0.5f);
            const bool neg = (iou < 0.4f);

            if (pos || neg) {
#pragma unroll
                for (int c = 0; c < C_CLS; ++c) {
                    float p = av[k * C_CLS + c];
                    p = fminf(fmaxf(p, 1e-4f), PHI);
                    const float tgt = pos ? lab[c] : 0.0f;
                    float loss;
                    if (tgt == 1.0f) {
                        const float q = 1.0f - p;
                        loss = 0.25f * (q * q) * (-logf(p));
                    } else {
                        loss = 0.75f * (p * p) * (-logf(1.0f - p));
                    }
                    att_sum += loss;
                }
            }
            if (pos) {
                ++np;
                const float acx = ax0 + 0.5f * aw;
                const float acy = ay0 + 0.5f * ah;
                const float t0 = ((gcx - acx) / aw) / 0.1f;
                const float t1 = ((gcy - acy) / ah) / 0.1f;
                const float t2 = logf(gw / aw) / 0.2f;
                const float t3 = logf(gh / ah) / 0.2f;
                const float4 r = *reinterpret_cast<const float4*>(regr + ((size_t)b * A_ANCH + a0 + k) * 4);
                float d;
                d = fabsf(t0 - r.x); rl_sum += (d <= TH) ? 4.5f * d * d : d - SUB;
                d = fabsf(t1 - r.y); rl_sum += (d <= TH) ? 4.5f * d * d : d - SUB;
                d = fabsf(t2 - r.z); rl_sum += (d <= TH) ? 4.5f * d * d : d - SUB;
                d = fabsf(t3 - r.w); rl_sum += (d <= TH) ? 4.5f * d * d : d - SUB;
            }
        }
    }

    // wave (64-lane) reduce
#pragma unroll
    for (int off = 32; off > 0; off >>= 1) {
        att_sum += __shfl_down(att_sum, off);
        rl_sum  += __shfl_down(rl_sum, off);
        np      += __shfl_down(np, off);
    }

    __shared__ float s_att[TPB / 64];
    __shared__ float s_rl[TPB / 64];
    __shared__ int   s_np[TPB / 64];
    const int wave = threadIdx.x >> 6;
    const int lane = threadIdx.x & 63;
    if (lane == 0) { s_att[wave] = att_sum; s_rl[wave] = rl_sum; s_np[wave] = np; }
    __syncthreads();
    if (threadIdx.x == 0) {
        float a0s = 0.0f, r0 = 0.0f;
        int n0 = 0;
#pragma unroll
        for (int w = 0; w < TPB / 64; ++w) { a0s += s_att[w]; r0 += s_rl[w]; n0 += s_np[w]; }
        atomicAdd(&att_acc[b], (double)a0s);
        if (r0 != 0.0f) atomicAdd(&rl_acc[b], (double)r0);
        if (n0 != 0)    atomicAdd(&np_acc[b], n0);
    }
}

__global__ void focal_finalize(
    const double* __restrict__ att_acc,
    const double* __restrict__ rl_acc,
    const int* __restrict__ np_acc,
    float* __restrict__ out)
{
    if (threadIdx.x == 0 && blockIdx.x == 0) {
        double am = 0.0, rm = 0.0;
        for (int b = 0; b < B_IMG; ++b) {
            const int np = np_acc[b];
            const double npf = (double)(np > 0 ? np : 1);
            am += att_acc[b] / npf;
            if (np > 0) rm += rl_acc[b] / (npf * 4.0);
        }
        out[0] = (float)(am / (double)B_IMG);
        out[1] = (float)(rm / (double)B_IMG);
    }
}

extern "C" void kernel_launch(void* const* d_in, const int* in_sizes, int n_in,
                              void* d_out, int out_size, void* d_ws, size_t ws_size,
                              hipStream_t stream) {
    const float* attr = (const float*)d_in[0];   // attributes (B,A,C)
    const float* regr = (const float*)d_in[1];   // regressions (B,A,4)
    const float* anch = (const float*)d_in[2];   // anchors (1,A,4)
    const float* ann  = (const float*)d_in[3];   // annotations (B,14)
    float* out = (float*)d_out;

    double* att_acc = (double*)d_ws;
    double* rl_acc  = att_acc + B_IMG;
    int*    np_acc  = (int*)(rl_acc + B_IMG);

    // zero the accumulators every launch (harness does not re-poison between replays)
    hipMemsetAsync(d_ws, 0, 2 * B_IMG * sizeof(double) + B_IMG * sizeof(int), stream);

    dim3 grid((A_ANCH + TPB * 2 - 1) / (TPB * 2), B_IMG);
    focal_main<<<grid, TPB, 0, stream>>>(attr, regr, anch, ann, att_acc, rl_acc, np_acc);
    focal_finalize<<<1, 64, 0, stream>>>(att_acc, rl_acc, np_acc, out);
}

// Round 3
// 23.386 us; speedup vs baseline: 3.5331x; 2.1377x over previous
//
#include <hip/hip_runtime.h>

// Problem constants (match reference)
constexpr int B_IMG = 8;
constexpr int A_ANCH = 150000;
constexpr int C_CLS = 10;
constexpr int TPB = 256;
// grid.x blocks over anchors (2 anchors/thread), grid.y = image
constexpr int NBX = (A_ANCH + TPB * 2 - 1) / (TPB * 2);   // 293

// ws layout: float att_part[B][NBX], float rl_part[B][NBX], float np_part[B][NBX]
// No atomics: every block stores its partials unconditionally; finalize reduces.
__global__ __launch_bounds__(TPB) void focal_main(
    const float* __restrict__ attr,   // (B, A, C)
    const float* __restrict__ regr,   // (B, A, 4)
    const float* __restrict__ anch,   // (A, 4)
    const float* __restrict__ ann,    // (B, 14)
    float* __restrict__ att_part,
    float* __restrict__ rl_part,
    float* __restrict__ np_part)
{
    const int b = blockIdx.y;
    const int a0 = (blockIdx.x * TPB + threadIdx.x) * 2;
    const bool valid = (a0 < A_ANCH);   // A even, so a0 valid => a0+1 valid

    // ---- issue ALL global loads for this thread upfront (independent, vectorized) ----
    float4 at4[5];   // 2 anchors x 10 classes
    float4 an4[2];   // 2 anchor boxes
    if (valid) {
        const float4* ap = reinterpret_cast<const float4*>(attr + ((size_t)b * A_ANCH + a0) * C_CLS);
#pragma unroll
        for (int j = 0; j < 5; ++j) at4[j] = ap[j];
        const float4* anp = reinterpret_cast<const float4*>(anch) + a0;
        an4[0] = anp[0];
        an4[1] = anp[1];
    }

    // annotation is wave-uniform -> scalar loads
    const float* annb = ann + b * 14;
    const float bx0 = annb[0], by0 = annb[1], bx1 = annb[2], by1 = annb[3];
    float lab[C_CLS];
#pragma unroll
    for (int c = 0; c < C_CLS; ++c) lab[c] = annb[4 + c];

    const float gw_raw = bx1 - bx0;
    const float gh_raw = by1 - by0;
    const float area = gw_raw * gh_raw;
    const float gcx = bx0 + 0.5f * gw_raw;
    const float gcy = by0 + 0.5f * gh_raw;
    const float gw = fmaxf(gw_raw, 1.0f);
    const float gh = fmaxf(gh_raw, 1.0f);

    const float TH  = (float)(1.0 / 9.0);
    const float SUB = (float)(0.5 / 9.0);
    const float PHI = (float)(1.0 - 0.0001);

    float att_sum = 0.0f;
    float rl_sum = 0.0f;
    int np = 0;

    if (valid) {
        float av[20];
#pragma unroll
        for (int j = 0; j < 5; ++j) {
            av[4 * j + 0] = at4[j].x;
            av[4 * j + 1] = at4[j].y;
            av[4 * j + 2] = at4[j].z;
            av[4 * j + 3] = at4[j].w;
        }

#pragma unroll
        for (int k = 0; k < 2; ++k) {
            const float ax0 = an4[k].x, ay0 = an4[k].y, ax1 = an4[k].z, ay1 = an4[k].w;
            const float aw = ax1 - ax0;
            const float ah = ay1 - ay0;
            float iw = fminf(ax1, bx1) - fmaxf(ax0, bx0);
            float ih = fminf(ay1, by1) - fmaxf(ay0, by0);
            iw = fmaxf(iw, 0.0f);
            ih = fmaxf(ih, 0.0f);
            const float inter = iw * ih;
            const float uni = fmaxf(aw * ah + area - inter, 1e-8f);
            const float iou = inter / uni;
            const bool pos = (iou >= 0.5f);
            const bool neg = (iou < 0.4f);

            if (pos || neg) {
#pragma unroll
                for (int c = 0; c < C_CLS; ++c) {
                    float p = av[k * C_CLS + c];
                    p = fminf(fmaxf(p, 1e-4f), PHI);
                    const float tgt = pos ? lab[c] : 0.0f;
                    float loss;
                    if (tgt == 1.0f) {
                        const float q = 1.0f - p;
                        loss = 0.25f * (q * q) * (-logf(p));
                    } else {
                        loss = 0.75f * (p * p) * (-logf(1.0f - p));
                    }
                    att_sum += loss;
                }
            }
            if (pos) {
                ++np;
                const float acx = ax0 + 0.5f * aw;
                const float acy = ay0 + 0.5f * ah;
                const float t0 = ((gcx - acx) / aw) / 0.1f;
                const float t1 = ((gcy - acy) / ah) / 0.1f;
                const float t2 = logf(gw / aw) / 0.2f;
                const float t3 = logf(gh / ah) / 0.2f;
                const float4 r = *reinterpret_cast<const float4*>(regr + ((size_t)b * A_ANCH + a0 + k) * 4);
                float d;
                d = fabsf(t0 - r.x); rl_sum += (d <= TH) ? 4.5f * d * d : d - SUB;
                d = fabsf(t1 - r.y); rl_sum += (d <= TH) ? 4.5f * d * d : d - SUB;
                d = fabsf(t2 - r.z); rl_sum += (d <= TH) ? 4.5f * d * d : d - SUB;
                d = fabsf(t3 - r.w); rl_sum += (d <= TH) ? 4.5f * d * d : d - SUB;
            }
        }
    }

    // wave (64-lane) reduce
#pragma unroll
    for (int off = 32; off > 0; off >>= 1) {
        att_sum += __shfl_down(att_sum, off);
        rl_sum  += __shfl_down(rl_sum, off);
        np      += __shfl_down(np, off);
    }

    __shared__ float s_att[TPB / 64];
    __shared__ float s_rl[TPB / 64];
    __shared__ int   s_np[TPB / 64];
    const int wave = threadIdx.x >> 6;
    const int lane = threadIdx.x & 63;
    if (lane == 0) { s_att[wave] = att_sum; s_rl[wave] = rl_sum; s_np[wave] = np; }
    __syncthreads();
    if (threadIdx.x == 0) {
        float a0s = 0.0f, r0 = 0.0f;
        int n0 = 0;
#pragma unroll
        for (int w = 0; w < TPB / 64; ++w) { a0s += s_att[w]; r0 += s_rl[w]; n0 += s_np[w]; }
        const int idx = b * NBX + blockIdx.x;
        att_part[idx] = a0s;            // plain stores, no atomics
        rl_part[idx]  = r0;
        np_part[idx]  = (float)n0;      // counts < 2^24, exact in float
    }
}

// One block, 8 waves: wave b tree-reduces image b's NBX partials.
__global__ __launch_bounds__(512) void focal_finalize(
    const float* __restrict__ att_part,
    const float* __restrict__ rl_part,
    const float* __restrict__ np_part,
    float* __restrict__ out)
{
    const int wave = threadIdx.x >> 6;
    const int lane = threadIdx.x & 63;
    float as = 0.0f, rs = 0.0f, ns = 0.0f;
    if (wave < B_IMG) {
        for (int i = lane; i < NBX; i += 64) {
            as += att_part[wave * NBX + i];
            rs += rl_part[wave * NBX + i];
            ns += np_part[wave * NBX + i];
        }
    }
#pragma unroll
    for (int off = 32; off > 0; off >>= 1) {
        as += __shfl_down(as, off);
        rs += __shfl_down(rs, off);
        ns += __shfl_down(ns, off);
    }
    __shared__ float sa[B_IMG], sr[B_IMG], sn[B_IMG];
    if (lane == 0 && wave < B_IMG) { sa[wave] = as; sr[wave] = rs; sn[wave] = ns; }
    __syncthreads();
    if (threadIdx.x == 0) {
        double am = 0.0, rm = 0.0;
        for (int b = 0; b < B_IMG; ++b) {
            const double npd = (double)sn[b];
            const double npf = npd > 0.0 ? npd : 1.0;
            am += (double)sa[b] / npf;
            if (npd > 0.0) rm += (double)sr[b] / (npf * 4.0);
        }
        out[0] = (float)(am / (double)B_IMG);
        out[1] = (float)(rm / (double)B_IMG);
    }
}

extern "C" void kernel_launch(void* const* d_in, const int* in_sizes, int n_in,
                              void* d_out, int out_size, void* d_ws, size_t ws_size,
                              hipStream_t stream) {
    const float* attr = (const float*)d_in[0];   // attributes (B,A,C)
    const float* regr = (const float*)d_in[1];   // regressions (B,A,4)
    const float* anch = (const float*)d_in[2];   // anchors (1,A,4)
    const float* ann  = (const float*)d_in[3];   // annotations (B,14)
    float* out = (float*)d_out;

    float* att_part = (float*)d_ws;
    float* rl_part  = att_part + B_IMG * NBX;
    float* np_part  = rl_part + B_IMG * NBX;
    // All partials are stored unconditionally every launch -> no memset needed.

    dim3 grid(NBX, B_IMG);
    focal_main<<<grid, TPB, 0, stream>>>(attr, regr, anch, ann, att_part, rl_part, np_part);
    focal_finalize<<<1, 512, 0, stream>>>(att_part, rl_part, np_part, out);
}